// Round 10
// baseline (25718.787 us; speedup 1.0000x reference)
//
#include <hip/hip_runtime.h>
#include <hip/hip_fp16.h>

typedef unsigned short ushort_t;
typedef unsigned int uint_t;

#define BN 512
#define LN 1024
#define FN 38
#define HN 256
#define ZDN 4
#define FXN 64
#define FZN 32

#define NT 512
#define NWG 256

__device__ __forceinline__ ushort_t f2h(float f) { return __half_as_ushort(__float2half(f)); }
__device__ __forceinline__ float h2f(ushort_t u) { return __half2float(__ushort_as_half(u)); }
__device__ __forceinline__ uint_t pk2(float a, float b) {
    return (uint_t)f2h(a) | ((uint_t)f2h(b) << 16);
}

#if defined(__has_builtin)
#if __has_builtin(__builtin_amdgcn_fdot2)
#define HAVE_FDOT2 1
#endif
#endif

typedef _Float16 hv2 __attribute__((ext_vector_type(2)));

__device__ __forceinline__ float dot2h(uint_t w, uint_t a, float acc) {
#ifdef HAVE_FDOT2
    return __builtin_amdgcn_fdot2(__builtin_bit_cast(hv2, w), __builtin_bit_cast(hv2, a), acc, false);
#else
    return acc + h2f((ushort_t)w) * h2f((ushort_t)a)
               + h2f((ushort_t)(w >> 16)) * h2f((ushort_t)(a >> 16));
#endif
}

// one uint4 of weights (8 k) x acts for 2 batch rows -> 16 dot2
__device__ __forceinline__ void dot16(uint4 w, uint4 a0, uint4 a1, float& s0, float& s1) {
    s0 = dot2h(w.x, a0.x, s0); s0 = dot2h(w.y, a0.y, s0);
    s0 = dot2h(w.z, a0.z, s0); s0 = dot2h(w.w, a0.w, s0);
    s1 = dot2h(w.x, a1.x, s1); s1 = dot2h(w.y, a1.y, s1);
    s1 = dot2h(w.z, a1.z, s1); s1 = dot2h(w.w, a1.w, s1);
}

__device__ __forceinline__ float sigmoidf_(float v) { return 1.0f / (1.0f + expf(-v)); }
__device__ __forceinline__ float softplusf_(float v) {
    return fmaxf(v, 0.0f) + log1pf(expf(-fabsf(v)));
}

// Unified lane-linear weight stream: 66 uint4 units, dst4[u*512 + t].
// Thread t: j2 = t>>1 (row), kh = t&1 (k-half). Gate k-slices: h[128kh,+128), x[48kh,+48).
//  u  0..15: RH  r-gate h   (-> LDS)   row j2,     k = 128kh + 8u
//  u 16..31: ZH  z-gate h   (stream)   row 256+j2, k = 128kh + 8(u-16)
//  u 32..37: ZX  z-gate x   (stream)   row 256+j2, xk = 48kh + 8(u-32)
//  u 38..43: RX  r-gate x   (stream)   row j2,     xk = 48kh + 8(u-38)
//  u 44..49: IN  in-gate x  (stream)   row 512+j2, xk = 48kh + 8(u-44)
//  u 50..61: HNR hn k-lo    (-> regs)  row 512+j2, k = 128kh + 8(u-50)
//  u 62..65: HNS hn k-hi    (stream)   row 512+j2, k = 128kh + 96 + 8(u-62)
__global__ __launch_bounds__(256) void repack_all(const float* __restrict__ W_ih,
                                                  const float* __restrict__ W_hh,
                                                  uint_t* __restrict__ dst) {
    int uid = blockIdx.x * 256 + threadIdx.x;       // uint index, total 66*2048
    if (uid >= 66 * 2048) return;
    int u = uid >> 11, rem = uid & 2047;
    int t = rem >> 2, w = rem & 3;
    int j2 = t >> 1, kh = t & 1;
    float v0, v1;
    if (u < 16)      { int k = 128 * kh + 8 * u + 2 * w;
                       v0 = W_hh[j2 * 256 + k]; v1 = W_hh[j2 * 256 + k + 1]; }
    else if (u < 32) { int k = 128 * kh + 8 * (u - 16) + 2 * w;
                       v0 = W_hh[(256 + j2) * 256 + k]; v1 = W_hh[(256 + j2) * 256 + k + 1]; }
    else if (u < 38) { int k = 48 * kh + 8 * (u - 32) + 2 * w;
                       v0 = W_ih[(256 + j2) * 96 + k]; v1 = W_ih[(256 + j2) * 96 + k + 1]; }
    else if (u < 44) { int k = 48 * kh + 8 * (u - 38) + 2 * w;
                       v0 = W_ih[j2 * 96 + k]; v1 = W_ih[j2 * 96 + k + 1]; }
    else if (u < 50) { int k = 48 * kh + 8 * (u - 44) + 2 * w;
                       v0 = W_ih[(512 + j2) * 96 + k]; v1 = W_ih[(512 + j2) * 96 + k + 1]; }
    else if (u < 62) { int k = 128 * kh + 8 * (u - 50) + 2 * w;
                       v0 = W_hh[(512 + j2) * 256 + k]; v1 = W_hh[(512 + j2) * 256 + k + 1]; }
    else             { int k = 128 * kh + 96 + 8 * (u - 62) + 2 * w;
                       v0 = W_hh[(512 + j2) * 256 + k]; v1 = W_hh[(512 + j2) * 256 + k + 1]; }
    dst[uid] = pk2(v0, v1);
}

// phi weights f16: [c(0..3 loc, 4..7 scale)][160 uints]
__global__ __launch_bounds__(256) void repack_wp(const float* __restrict__ Wp_loc,
                                                 const float* __restrict__ Wp_scale,
                                                 uint_t* __restrict__ wpg) {
    int uid = blockIdx.x * 256 + threadIdx.x;
    if (uid >= 8 * 160) return;
    int c = uid / 160, u = uid % 160;
    const float* src = (c < 4) ? (Wp_loc + c * 320) : (Wp_scale + (c - 4) * 320);
    wpg[uid] = pk2(src[2 * u], src[2 * u + 1]);
}

// theta weights f16: [38][144 uints], k-order cat(fz, h)
__global__ __launch_bounds__(256) void repack_wt(const float* __restrict__ Wt_loc,
                                                 uint_t* __restrict__ wtg) {
    int uid = blockIdx.x * 256 + threadIdx.x;
    if (uid >= 38 * 144) return;
    wtg[uid] = pk2(Wt_loc[2 * uid], Wt_loc[2 * uid + 1]);
}

// fx = relu(x @ Wx^T + bx) for all (b,l), stored f16-packed [B][L][64].
__global__ __launch_bounds__(256) void fx_pre(const float* __restrict__ x,
                                              const float* __restrict__ Wx,
                                              const float* __restrict__ bx,
                                              ushort_t* __restrict__ fxbuf) {
    __shared__ float w[FXN][FN + 1];
    __shared__ float bxs[FXN];
    int t = threadIdx.x;
    for (int i = t; i < FXN * FN; i += 256) w[i / FN][i % FN] = Wx[i];
    if (t < FXN) bxs[t] = bx[t];
    __syncthreads();
    size_t id = (size_t)blockIdx.x * 256 + t;
    const float* xr = x + id * FN;
    float xv[FN];
#pragma unroll
    for (int f = 0; f < FN; ++f) xv[f] = xr[f];
    uint4* dst = (uint4*)(fxbuf + id * FXN);
#pragma unroll
    for (int e8 = 0; e8 < 8; ++e8) {
        float a[8];
#pragma unroll
        for (int u = 0; u < 8; ++u) {
            int e = e8 * 8 + u;
            float acc = bxs[e];
#pragma unroll
            for (int f = 0; f < FN; ++f) acc += xv[f] * w[e][f];
            a[u] = fmaxf(acc, 0.0f);
        }
        uint4 o;
        o.x = pk2(a[0], a[1]); o.y = pk2(a[2], a[3]);
        o.z = pk2(a[4], a[5]); o.w = pk2(a[6], a[7]);
        dst[e8] = o;
    }
}

template <bool FXPRE>
__global__ __launch_bounds__(NT)
void vrnn_main(
    const float* __restrict__ x, const float* __restrict__ eps,
    const float* __restrict__ Wx, const float* __restrict__ bx,
    const float* __restrict__ Wz1, const float* __restrict__ bz1,
    const float* __restrict__ Wz2, const float* __restrict__ bz2,
    const float* __restrict__ bp_loc, const float* __restrict__ bp_scale,
    const float* __restrict__ bt_loc,
    const float* __restrict__ b_ih, const float* __restrict__ b_hh,
    const uint_t* __restrict__ wstream, const uint_t* __restrict__ wpg,
    const uint_t* __restrict__ wtg, const ushort_t* __restrict__ fxbuf,
    float* __restrict__ out)
{
    __shared__ __attribute__((aligned(16))) uint_t rhw[16 * 512 * 4];   // 128 KB r-gate h, lane-linear
    __shared__ uint_t wpH[8 * 162];                                     // phi weights (padded)
    __shared__ __attribute__((aligned(16))) uint_t actp[2][2][176];     // f16 acts, dbuf
    __shared__ float pp[2][8][16];
    __shared__ float wz1s[16][ZDN];
    __shared__ float wz2s[FZN][16];
    __shared__ float bz1s[16], bz2s[FZN], btls[FN], bpls[ZDN], bpss[ZDN];
    __shared__ float epsb[2][ZDN];

    const int t = threadIdx.x;
    const int b0 = blockIdx.x * 2;
    const int j2 = t >> 1, kh = t & 1;

    const uint4* WS4 = (const uint4*)wstream;
    const uint4* ZH  = WS4 + 16 * 512 + t;
    const uint4* ZX  = WS4 + 32 * 512 + t;
    const uint4* RX  = WS4 + 38 * 512 + t;
    const uint4* INW = WS4 + 44 * 512 + t;
    const uint4* HNS = WS4 + 62 * 512 + t;

    // ---- one-time LDS init
    {
        uint4* rd = (uint4*)rhw;
        for (int i = t; i < 16 * 512; i += NT) rd[i] = WS4[i];
    }
    for (int i = t; i < 8 * 160; i += NT) wpH[(i / 160) * 162 + (i % 160)] = wpg[i];
    if (t < 64) ((float*)wz1s)[t] = Wz1[t];
    for (int i = t; i < FZN * 16; i += NT) ((float*)wz2s)[i] = Wz2[i];
    if (t < 16) bz1s[t] = bz1[t];
    if (t >= 32 && t < 64) bz2s[t - 32] = bz2[t - 32];
    if (t >= 64 && t < 64 + FN) btls[t - 64] = bt_loc[t - 64];
    if (t >= 128 && t < 132) bpls[t - 128] = bp_loc[t - 128];
    if (t >= 160 && t < 164) bpss[t - 160] = bp_scale[t - 160];
    // zero h region of buffer 0; prefill l=0 eps / fx
    if (t < 256) actp[0][t >> 7][t & 127] = 0u;
    if (t >= 448 && t < 456) {
        int m = (t >> 2) & 1, c = t & 3;
        epsb[m][c] = eps[(size_t)(b0 + m) * ZDN + c];
    }
    if (FXPRE && t >= 480 && t < 496) {
        int m = (t >> 3) & 1, p = t & 7;
        uint4 v = *(const uint4*)(fxbuf + ((size_t)(b0 + m) * LN) * FXN + p * 8);
        uint_t* d = &actp[0][m][128 + p * 4];
        d[0] = v.x; d[1] = v.y; d[2] = v.z; d[3] = v.w;
    }

    // ---- persistent register weights: hn k-low = 12 uint4 = 48 VGPRs
    uint4 whn[12];
#pragma unroll
    for (int i = 0; i < 12; ++i) whn[i] = WS4[(50 + i) * 512 + t];

    const float bsr_o = b_ih[j2] + b_hh[j2];
    const float bsz_o = b_ih[HN + j2] + b_hh[HN + j2];
    const float bin_o = b_ih[2 * HN + j2];
    const float bhn_o = b_hh[2 * HN + j2];
    float h_own = 0.0f;          // h[m=kh][j2], f32, register-resident

    __syncthreads();

#pragma unroll 1
    for (int l = 0; l < LN; ++l) {
        const int cur = l & 1, nxt = cur ^ 1;
        const uint_t* Au0 = actp[cur][0];
        const uint_t* Au1 = actp[cur][1];
        const uint4* A0_4 = (const uint4*)Au0;
        const uint4* A1_4 = (const uint4*)Au1;

        if (!FXPRE) {
            if (t < 64) {
                int m = t >> 5, e2 = t & 31;
                const float* xr = x + ((size_t)(b0 + m) * LN + l) * FN;
                float a0 = bx[2 * e2], a1 = bx[2 * e2 + 1];
                const float* w0 = Wx + (2 * e2) * FN;
                const float* w1 = w0 + FN;
#pragma unroll
                for (int f = 0; f < FN; ++f) { float xv = xr[f]; a0 += xv * w0[f]; a1 += xv * w1[f]; }
                actp[cur][m][128 + e2] = pk2(fmaxf(a0, 0.0f), fmaxf(a1, 0.0f));
            }
            if (t >= 64 && t < 72) {
                int m = (t >> 2) & 1, c = t & 3;
                epsb[m][c] = eps[((size_t)l * BN + b0 + m) * ZDN + c];
            }
            __syncthreads();
        }

        // next-step input prefetch (wave 7)
        float pf_eps = 0.0f;
        uint4 pf_fx = {0, 0, 0, 0};
        if (FXPRE) {
            int lp = (l + 1 < LN) ? l + 1 : LN - 1;
            if (t >= 448 && t < 456) {
                int m = (t >> 2) & 1, c = t & 3;
                pf_eps = eps[((size_t)lp * BN + b0 + m) * ZDN + c];
            }
            if (t >= 480 && t < 496) {
                int m = (t >> 3) & 1, p = t & 7;
                pf_fx = *(const uint4*)(fxbuf + ((size_t)(b0 + m) * LN + lp) * FXN + p * 8);
            }
        }

        // ---- phi partials (t<256): f16 acts x f16 weights
        if (t < 256) {
            int m = t >> 7, r = t & 127, c = r >> 4, ks = r & 15;
            const uint2* wv = (const uint2*)&wpH[c * 162 + ks * 10];
            const uint2* av = (const uint2*)((m ? Au1 : Au0) + ks * 10);
            float acc = 0.0f;
#pragma unroll
            for (int i = 0; i < 5; ++i) {
                uint2 w = wv[i], a = av[i];
                acc = dot2h(w.x, a.x, acc); acc = dot2h(w.y, a.y, acc);
            }
            pp[m][c][ks] = acc;
        }
        __syncthreads();   // sync1: pp ready

        // ---- CDE (t<64, wave 0) overlapped with the big h-phase dots (all waves)
        if (t < 64) {
            int m = t >> 5, qq = t & 31;
            float zz[ZDN];
#pragma unroll
            for (int c = 0; c < ZDN; ++c) {
                float lo = bpls[c], sc = bpss[c];
#pragma unroll
                for (int ks = 0; ks < 16; ++ks) { lo += pp[m][c][ks]; sc += pp[m][c + 4][ks]; }
                zz[c] = lo + softplusf_(sc) * epsb[m][c];
            }
            float acc = bz2s[qq];
#pragma unroll
            for (int k = 0; k < 16; ++k) {
                float a = bz1s[k];
#pragma unroll
                for (int c = 0; c < ZDN; ++c) a += zz[c] * wz1s[k][c];
                acc += fmaxf(a, 0.0f) * wz2s[qq][k];
            }
            float v = fmaxf(acc, 0.0f);
            float oth = __shfl_xor(v, 1);
            if (!(qq & 1)) actp[cur][m][160 + (qq >> 1)] = pk2(v, oth);
        }

        // ---- h-phase: r (LDS), z (stream), hn (regs + stream tail); shared act reads
        float ar0 = 0, ar1 = 0, az0 = 0, az1 = 0, ah0 = 0, ah1 = 0;
        {
            const uint4* rh4 = ((const uint4*)rhw) + t;
#pragma unroll
            for (int b = 0; b < 16; ++b) {
                uint4 a0 = A0_4[16 * kh + b];
                uint4 a1 = A1_4[16 * kh + b];
                uint4 zw = ZH[b * 512];
                uint4 rw = rh4[b * 512];
                dot16(rw, a0, a1, ar0, ar1);
                dot16(zw, a0, a1, az0, az1);
                uint4 hw = (b < 12) ? whn[b] : HNS[(b - 12) * 512];
                dot16(hw, a0, a1, ah0, ah1);
            }
        }
        __syncthreads();   // sync2: fz ready

        // ---- x-phase: r/z/in over x slice (fx | fz); shared act reads
        float ai0 = 0, ai1 = 0;
#pragma unroll
        for (int c = 0; c < 6; ++c) {
            uint4 a0 = A0_4[32 + 6 * kh + c];
            uint4 a1 = A1_4[32 + 6 * kh + c];
            dot16(RX[c * 512], a0, a1, ar0, ar1);
            dot16(ZX[c * 512], a0, a1, az0, az1);
            dot16(INW[c * 512], a0, a1, ai0, ai1);
        }

        // theta (t<304): streamed weights, 4-way k-split (reads fz, post-sync2)
        if (t < 304) {
            int o = t >> 2, s4 = t & 3, f = o >> 1, m = o & 1;
            const uint4* wt4 = ((const uint4*)wtg) + f * 36;
            const uint4* ap = m ? A1_4 : A0_4;
            float acc = 0.0f;
#pragma unroll
            for (int i2 = 0; i2 < 9; ++i2) {
                int i = s4 * 9 + i2;
                uint4 w = wt4[i];
                uint4 a = (i < 4) ? ap[40 + i] : ap[i - 4];   // fz | h
                acc = dot2h(w.x, a.x, acc); acc = dot2h(w.y, a.y, acc);
                acc = dot2h(w.z, a.z, acc); acc = dot2h(w.w, a.w, acc);
            }
            acc += __shfl_xor(acc, 1);
            acc += __shfl_xor(acc, 2);
            if (!s4) out[((size_t)(b0 + m) * LN + l) * FN + f] = acc + btls[f];
        }

        // ---- combine k-halves (pair lanes) + gates + h update
        {
            float Tr0 = ar0 + __shfl_xor(ar0, 1);
            float Tr1 = ar1 + __shfl_xor(ar1, 1);
            float Tz0 = az0 + __shfl_xor(az0, 1);
            float Tz1 = az1 + __shfl_xor(az1, 1);
            float Ti0 = ai0 + __shfl_xor(ai0, 1);
            float Ti1 = ai1 + __shfl_xor(ai1, 1);
            float Th0 = ah0 + __shfl_xor(ah0, 1);
            float Th1 = ah1 + __shfl_xor(ah1, 1);
            float gr = kh ? Tr1 : Tr0;
            float gz = kh ? Tz1 : Tz0;
            float gi = kh ? Ti1 : Ti0;
            float gh = kh ? Th1 : Th0;
            float r_ = sigmoidf_(gr + bsr_o);
            float z_ = sigmoidf_(gz + bsz_o);
            float n_ = tanhf(gi + bin_o + r_ * (gh + bhn_o));
            float hnew = (1.0f - z_) * n_ + z_ * h_own;
            h_own = hnew;
            float hp = __shfl_xor(hnew, 2);            // pair rows j2, j2^1
            if (!(t & 2)) actp[nxt][kh][j2 >> 1] = pk2(hnew, hp);
        }

        // park prefetched inputs into next-step buffers
        if (FXPRE) {
            if (t >= 448 && t < 456) { int m = (t >> 2) & 1, c = t & 3; epsb[m][c] = pf_eps; }
            if (t >= 480 && t < 496) {
                int m = (t >> 3) & 1, p = t & 7;
                uint_t* d = &actp[nxt][m][128 + p * 4];
                d[0] = pf_fx.x; d[1] = pf_fx.y; d[2] = pf_fx.z; d[3] = pf_fx.w;
            }
        }
        __syncthreads();   // sync3
    }
}

extern "C" void kernel_launch(void* const* d_in, const int* in_sizes, int n_in,
                              void* d_out, int out_size, void* d_ws, size_t ws_size,
                              hipStream_t stream) {
    const float* x        = (const float*)d_in[0];
    const float* eps      = (const float*)d_in[1];
    const float* Wx       = (const float*)d_in[2];
    const float* bx       = (const float*)d_in[3];
    const float* Wz1      = (const float*)d_in[4];
    const float* bz1      = (const float*)d_in[5];
    const float* Wz2      = (const float*)d_in[6];
    const float* bz2      = (const float*)d_in[7];
    const float* Wp_loc   = (const float*)d_in[8];
    const float* bp_loc   = (const float*)d_in[9];
    const float* Wp_scale = (const float*)d_in[10];
    const float* bp_scale = (const float*)d_in[11];
    const float* Wt_loc   = (const float*)d_in[12];
    const float* bt_loc   = (const float*)d_in[13];
    const float* W_ih     = (const float*)d_in[16];
    const float* W_hh     = (const float*)d_in[17];
    const float* b_ih     = (const float*)d_in[18];
    const float* b_hh     = (const float*)d_in[19];
    float* out = (float*)d_out;

    const size_t wsU  = (size_t)66 * 2048;        // unified stream, uints
    const size_t wpU  = 8 * 160;
    const size_t wtU  = 38 * 144;
    const size_t fxS  = (size_t)BN * LN * FXN;    // shorts

    uint_t* wstream = (uint_t*)d_ws;
    uint_t* wpg     = wstream + wsU;
    uint_t* wtg     = wpg + wpU;
    ushort_t* fxbuf = (ushort_t*)(wtg + wtU);

    repack_all<<<(int)((wsU + 255) / 256), 256, 0, stream>>>(W_ih, W_hh, wstream);
    repack_wp<<<5, 256, 0, stream>>>(Wp_loc, Wp_scale, wpg);
    repack_wt<<<22, 256, 0, stream>>>(Wt_loc, wtg);

    if (ws_size >= (wsU + wpU + wtU) * 4 + fxS * 2) {
        fx_pre<<<BN * LN / 256, 256, 0, stream>>>(x, Wx, bx, fxbuf);
        vrnn_main<true><<<NWG, NT, 0, stream>>>(
            x, eps, Wx, bx, Wz1, bz1, Wz2, bz2, bp_loc, bp_scale, bt_loc,
            b_ih, b_hh, wstream, wpg, wtg, fxbuf, out);
    } else {
        vrnn_main<false><<<NWG, NT, 0, stream>>>(
            x, eps, Wx, bx, Wz1, bz1, Wz2, bz2, bp_loc, bp_scale, bt_loc,
            b_ih, b_hh, wstream, wpg, wtg, (const ushort_t*)nullptr, out);
    }
}

// Round 11
// 12931.789 us; speedup vs baseline: 1.9888x; 1.9888x over previous
//
#include <hip/hip_runtime.h>
#include <hip/hip_fp16.h>

typedef unsigned short ushort_t;
typedef unsigned int uint_t;

#define BN 512
#define LN 1024
#define FN 38
#define HN 256
#define ZDN 4
#define FXN 64
#define FZN 32

#define NT 512
#define NWG 16
#define BT 32

// weight-fragment entry bases (entry = 64 lanes x 16 B = 1 KB)
#define RB 0      // r gate:  16 mt x 11 ks
#define ZB 176    // z gate:  16 mt x 11 ks
#define HB 352    // hn gate: 16 mt x 8 ks (h only)
#define IB 480    // in gate: 16 mt x 3 ks (x only)
#define TB 528    // theta:   3 mt x 9 ks ([fz|h])
#define PB 555    // phi:     1 mt x 10 ks ([h|fx])
#define NENT 565

__device__ __forceinline__ ushort_t f2h(float f) { return __half_as_ushort(__float2half(f)); }
__device__ __forceinline__ float h2f(ushort_t u) { return __half2float(__ushort_as_half(u)); }
__device__ __forceinline__ uint_t pk2(float a, float b) {
    return (uint_t)f2h(a) | ((uint_t)f2h(b) << 16);
}
__device__ __forceinline__ float sigmoidf_(float v) { return 1.0f / (1.0f + expf(-v)); }
__device__ __forceinline__ float softplusf_(float v) {
    return fmaxf(v, 0.0f) + log1pf(expf(-fabsf(v)));
}

typedef _Float16 h8 __attribute__((ext_vector_type(8)));
typedef float f4 __attribute__((ext_vector_type(4)));
#define MFMA(A, B, C) __builtin_amdgcn_mfma_f32_16x16x32_f16((A), (B), (C), 0, 0, 0)
__device__ __forceinline__ h8 bch8(uint4 v) { return __builtin_bit_cast(h8, v); }

// A-frag layout per entry: lane ln holds row = ln&15, k = (ln>>4)*8 + i (i=0..7).
// act k-space: 0..255 h (W_hh cols), 256..319 fx (W_ih 0..63), 320..351 fz (W_ih 64..95)
__global__ __launch_bounds__(256) void repack_frags(
    const float* __restrict__ W_ih, const float* __restrict__ W_hh,
    const float* __restrict__ Wt_loc,
    const float* __restrict__ Wp_loc, const float* __restrict__ Wp_scale,
    ushort_t* __restrict__ wfrag) {
    int idx = blockIdx.x * 256 + threadIdx.x;        // over NENT*512 f16
    if (idx >= NENT * 512) return;
    int e = idx >> 9, r512 = idx & 511, ln = r512 >> 3, i = r512 & 7;
    int row = ln & 15, kl = ((ln >> 4) << 3) + i;    // kl in 0..31
    float v = 0.0f;
    if (e < ZB) {                       // r
        int mt = e / 11, ks = e % 11, j = mt * 16 + row, ak = ks * 32 + kl;
        v = (ak < 256) ? W_hh[j * 256 + ak] : W_ih[j * 96 + ak - 256];
    } else if (e < HB) {                // z
        int e2 = e - ZB, mt = e2 / 11, ks = e2 % 11, j = mt * 16 + row, ak = ks * 32 + kl;
        v = (ak < 256) ? W_hh[(256 + j) * 256 + ak] : W_ih[(256 + j) * 96 + ak - 256];
    } else if (e < IB) {                // hn (h part)
        int e2 = e - HB, mt = e2 / 8, ks = e2 % 8, j = mt * 16 + row;
        v = W_hh[(512 + j) * 256 + ks * 32 + kl];
    } else if (e < TB) {                // in (x part)
        int e2 = e - IB, mt = e2 / 3, ksx = e2 % 3, j = mt * 16 + row;
        v = W_ih[(512 + j) * 96 + ksx * 32 + kl];
    } else if (e < PB) {                // theta, k-order [fz | h]
        int e2 = e - TB, mtt = e2 / 9, tks = e2 % 9, f = mtt * 16 + row;
        int col = (tks == 0) ? kl : 32 + (tks - 1) * 32 + kl;
        v = (f < FN) ? Wt_loc[f * 288 + col] : 0.0f;
    } else {                            // phi: rows 0-3 loc, 4-7 scale, k [h|fx]
        int ks = e - PB, col = ks * 32 + kl;
        if (row < 4) v = Wp_loc[row * 320 + col];
        else if (row < 8) v = Wp_scale[(row - 4) * 320 + col];
    }
    wfrag[idx] = f2h(v);
}

// fx = relu(x @ Wx^T + bx) for all (b,l), stored f16-packed [B][L][64].
__global__ __launch_bounds__(256) void fx_pre(const float* __restrict__ x,
                                              const float* __restrict__ Wx,
                                              const float* __restrict__ bx,
                                              ushort_t* __restrict__ fxbuf) {
    __shared__ float w[FXN][FN + 1];
    __shared__ float bxs[FXN];
    int t = threadIdx.x;
    for (int i = t; i < FXN * FN; i += 256) w[i / FN][i % FN] = Wx[i];
    if (t < FXN) bxs[t] = bx[t];
    __syncthreads();
    size_t id = (size_t)blockIdx.x * 256 + t;
    const float* xr = x + id * FN;
    float xv[FN];
#pragma unroll
    for (int f = 0; f < FN; ++f) xv[f] = xr[f];
    uint4* dst = (uint4*)(fxbuf + id * FXN);
#pragma unroll
    for (int e8 = 0; e8 < 8; ++e8) {
        float a[8];
#pragma unroll
        for (int u = 0; u < 8; ++u) {
            int e = e8 * 8 + u;
            float acc = bxs[e];
#pragma unroll
            for (int f = 0; f < FN; ++f) acc += xv[f] * w[e][f];
            a[u] = fmaxf(acc, 0.0f);
        }
        uint4 o;
        o.x = pk2(a[0], a[1]); o.y = pk2(a[2], a[3]);
        o.z = pk2(a[4], a[5]); o.w = pk2(a[6], a[7]);
        dst[e8] = o;
    }
}

// act-frag index: buffer buf, n-tile nt, k-step ks -> base in ushorts
#define AIDX(buf, nt, ks) ((((buf) * 2 + (nt)) * 11 + (ks)) * 512)

template <bool FXPRE>
__global__ __launch_bounds__(NT) void vrnn_mfma(
    const float* __restrict__ x, const float* __restrict__ eps,
    const float* __restrict__ Wx, const float* __restrict__ bx,
    const float* __restrict__ Wz1, const float* __restrict__ bz1,
    const float* __restrict__ Wz2, const float* __restrict__ bz2,
    const float* __restrict__ bp_loc, const float* __restrict__ bp_scale,
    const float* __restrict__ bt_loc,
    const float* __restrict__ b_ih, const float* __restrict__ b_hh,
    const ushort_t* __restrict__ wfrag, const ushort_t* __restrict__ fxbuf,
    float* __restrict__ out)
{
    __shared__ __attribute__((aligned(16))) ushort_t actf[2 * 2 * 11 * 512]; // 45 KB frags
    __shared__ __attribute__((aligned(16))) uint_t phif[10 * 64 * 4];        // phi A-frags
    __shared__ float pp[8][32];
    __shared__ float bsr[HN], bsz[HN], bin_[HN], bhn_[HN];
    __shared__ float wz1s[16][ZDN], wz2s[FZN][16];
    __shared__ float bz1s[16], bz2s[FZN], btls[FN], bpls[ZDN], bpss[ZDN];
    __shared__ float wxs[FXN][FN + 2], bxs[FXN];     // tier-B fx weights

    const int t = threadIdx.x;
    const int w = t >> 6, ln = t & 63;
    const int b0 = blockIdx.x * BT;
    const uint4* WL = ((const uint4*)wfrag) + ln;    // lane-offset entry table

    // ---- one-time init
    {
        const uint_t* wfu = (const uint_t*)wfrag;
        for (int i = t; i < 10 * 256; i += NT) phif[i] = wfu[PB * 256 + i];
    }
    if (t < HN) {
        bsr[t] = b_ih[t] + b_hh[t];
        bsz[t] = b_ih[HN + t] + b_hh[HN + t];
        bin_[t] = b_ih[2 * HN + t];
        bhn_[t] = b_hh[2 * HN + t];
    }
    if (t >= 256 && t < 320) ((float*)wz1s)[t - 256] = Wz1[t - 256];
    for (int i = t; i < FZN * 16; i += NT) ((float*)wz2s)[i] = Wz2[i];
    if (t < 16) bz1s[t] = bz1[t];
    if (t >= 32 && t < 64) bz2s[t - 32] = bz2[t - 32];
    if (t >= 64 && t < 64 + FN) btls[t - 64] = bt_loc[t - 64];
    if (t >= 128 && t < 132) bpls[t - 128] = bp_loc[t - 128];
    if (t >= 160 && t < 164) bpss[t - 160] = bp_scale[t - 164 + 4];
    if (!FXPRE) {
        for (int i = t; i < FXN * FN; i += NT) wxs[i / FN][i % FN] = Wx[i];
        if (t >= 320 && t < 384) bxs[t - 320] = bx[t - 320];
    }
    // zero h-region of buffer 0 (ksteps 0..7, both nt)
    for (int i = t; i < 2 * 8 * 512; i += NT) {
        int nt = i >> 12, rem = i & 4095;
        actf[AIDX(0, nt, rem >> 9) + (rem & 511)] = 0;
    }
    __syncthreads();
    // fx(l=0) into buffer 0
    if (FXPRE) {
        if (t < 256) {
            int b = t >> 3, ch = t & 7;
            uint4 v = ((const uint4*)fxbuf)[((size_t)(b0 + b) * LN) * 8 + ch];
            int dst = AIDX(0, b >> 4, 8 + (ch >> 2)) + ((ch & 3) * 16 + (b & 15)) * 8;
            *(uint4*)&actf[dst] = v;
        }
    } else if (t < 256) {
        int b = t >> 3, ch = t & 7;
        const float* xr = x + ((size_t)(b0 + b) * LN) * FN;
        uint_t o[4];
#pragma unroll
        for (int p = 0; p < 4; ++p) {
            float a0 = bxs[ch * 8 + 2 * p], a1 = bxs[ch * 8 + 2 * p + 1];
#pragma unroll
            for (int f = 0; f < FN; ++f) {
                float xv = xr[f];
                a0 += xv * wxs[ch * 8 + 2 * p][f];
                a1 += xv * wxs[ch * 8 + 2 * p + 1][f];
            }
            o[p] = pk2(fmaxf(a0, 0.0f), fmaxf(a1, 0.0f));
        }
        int dst = AIDX(0, b >> 4, 8 + (ch >> 2)) + ((ch & 3) * 16 + (b & 15)) * 8;
        *(uint4*)&actf[dst] = make_uint4(o[0], o[1], o[2], o[3]);
    }
    __syncthreads();

    const int mtA = 2 * w, mtB = 2 * w + 1;

#pragma unroll 1
    for (int l = 0; l < LN; ++l) {
        const int cur = l & 1, nxt = cur ^ 1;

        f4 ra0 = {0,0,0,0}, ra1 = {0,0,0,0}, rb0 = {0,0,0,0}, rb1 = {0,0,0,0};
        f4 za0 = {0,0,0,0}, za1 = {0,0,0,0}, zb0 = {0,0,0,0}, zb1 = {0,0,0,0};
        f4 na0 = {0,0,0,0}, na1 = {0,0,0,0}, nb0 = {0,0,0,0}, nb1 = {0,0,0,0};
        f4 ia0 = {0,0,0,0}, ia1 = {0,0,0,0}, ib0 = {0,0,0,0}, ib1 = {0,0,0,0};
        f4 tp = {0,0,0,0};    // theta (waves 0-5) / phi (waves 6-7)

        // eps prefetch for CDE threads
        float4 pfe = {0, 0, 0, 0};
        if (t < 256) pfe = *(const float4*)&eps[((size_t)l * BN + b0 + (t >> 3)) * ZDN];

        // ---- Phase A: all MFMA except fz (kstep 10)
#pragma unroll 2
        for (int ks = 0; ks < 8; ++ks) {          // h ksteps
            h8 B0 = *(const h8*)&actf[AIDX(cur, 0, ks) + ln * 8];
            h8 B1 = *(const h8*)&actf[AIDX(cur, 1, ks) + ln * 8];
            uint4 aw;
            aw = WL[(RB + mtA * 11 + ks) * 64]; ra0 = MFMA(bch8(aw), B0, ra0); ra1 = MFMA(bch8(aw), B1, ra1);
            aw = WL[(RB + mtB * 11 + ks) * 64]; rb0 = MFMA(bch8(aw), B0, rb0); rb1 = MFMA(bch8(aw), B1, rb1);
            aw = WL[(ZB + mtA * 11 + ks) * 64]; za0 = MFMA(bch8(aw), B0, za0); za1 = MFMA(bch8(aw), B1, za1);
            aw = WL[(ZB + mtB * 11 + ks) * 64]; zb0 = MFMA(bch8(aw), B0, zb0); zb1 = MFMA(bch8(aw), B1, zb1);
            aw = WL[(HB + mtA * 8 + ks) * 64];  na0 = MFMA(bch8(aw), B0, na0); na1 = MFMA(bch8(aw), B1, na1);
            aw = WL[(HB + mtB * 8 + ks) * 64];  nb0 = MFMA(bch8(aw), B0, nb0); nb1 = MFMA(bch8(aw), B1, nb1);
            if (w < 6) {                          // theta h-part: tks = ks+1
                aw = WL[(TB + (w >> 1) * 9 + ks + 1) * 64];
                tp = MFMA(bch8(aw), (w & 1) ? B1 : B0, tp);
            } else {                              // phi h-part
                uint4 pa = *(const uint4*)&phif[(ks * 64 + ln) * 4];
                tp = MFMA(bch8(pa), (w == 7) ? B1 : B0, tp);
            }
        }
#pragma unroll
        for (int ks = 8; ks < 10; ++ks) {         // fx ksteps
            h8 B0 = *(const h8*)&actf[AIDX(cur, 0, ks) + ln * 8];
            h8 B1 = *(const h8*)&actf[AIDX(cur, 1, ks) + ln * 8];
            uint4 aw;
            aw = WL[(RB + mtA * 11 + ks) * 64]; ra0 = MFMA(bch8(aw), B0, ra0); ra1 = MFMA(bch8(aw), B1, ra1);
            aw = WL[(RB + mtB * 11 + ks) * 64]; rb0 = MFMA(bch8(aw), B0, rb0); rb1 = MFMA(bch8(aw), B1, rb1);
            aw = WL[(ZB + mtA * 11 + ks) * 64]; za0 = MFMA(bch8(aw), B0, za0); za1 = MFMA(bch8(aw), B1, za1);
            aw = WL[(ZB + mtB * 11 + ks) * 64]; zb0 = MFMA(bch8(aw), B0, zb0); zb1 = MFMA(bch8(aw), B1, zb1);
            aw = WL[(IB + mtA * 3 + (ks - 8)) * 64]; ia0 = MFMA(bch8(aw), B0, ia0); ia1 = MFMA(bch8(aw), B1, ia1);
            aw = WL[(IB + mtB * 3 + (ks - 8)) * 64]; ib0 = MFMA(bch8(aw), B0, ib0); ib1 = MFMA(bch8(aw), B1, ib1);
            if (w >= 6) {
                uint4 pa = *(const uint4*)&phif[(ks * 64 + ln) * 4];
                tp = MFMA(bch8(pa), (w == 7) ? B1 : B0, tp);
            }
        }
        if (w >= 6 && (ln >> 4) < 2) {            // dump phi D -> pp
            int nt = w - 6;
#pragma unroll
            for (int q = 0; q < 4; ++q) pp[(ln >> 4) * 4 + q][nt * 16 + (ln & 15)] = tp[q];
        }
        __syncthreads();

        // ---- CDE: z -> f1 -> fz (threads 0..255); fx(l+1) prefetch (256..511)
        if (t < 256) {
            int b = t >> 3, part = t & 7;
            float ez[4] = {pfe.x, pfe.y, pfe.z, pfe.w};
            float zz[4];
#pragma unroll
            for (int c = 0; c < 4; ++c)
                zz[c] = pp[c][b] + bpls[c] + softplusf_(pp[4 + c][b] + bpss[c]) * ez[c];
            float f1v[16];
#pragma unroll
            for (int k = 0; k < 16; ++k) {
                float a = bz1s[k];
#pragma unroll
                for (int c = 0; c < 4; ++c) a += zz[c] * wz1s[k][c];
                f1v[k] = fmaxf(a, 0.0f);
            }
            float v4[4];
#pragma unroll
            for (int oq = 0; oq < 4; ++oq) {
                int o = part * 4 + oq;
                float acc = bz2s[o];
#pragma unroll
                for (int k = 0; k < 16; ++k) acc += f1v[k] * wz2s[o][k];
                v4[oq] = fmaxf(acc, 0.0f);
            }
            uint2 pk; pk.x = pk2(v4[0], v4[1]); pk.y = pk2(v4[2], v4[3]);
            int dst = AIDX(cur, b >> 4, 10) + (((part >> 1) & 3) * 16 + (b & 15)) * 8 + (part & 1) * 4;
            *(uint2*)&actf[dst] = pk;
        } else {
            int tid = t - 256, b = tid >> 3, ch = tid & 7;
            int lp = (l + 1 < LN) ? l + 1 : LN - 1;
            int dst = AIDX(nxt, b >> 4, 8 + (ch >> 2)) + ((ch & 3) * 16 + (b & 15)) * 8;
            if (FXPRE) {
                uint4 v = ((const uint4*)fxbuf)[((size_t)(b0 + b) * LN + lp) * 8 + ch];
                *(uint4*)&actf[dst] = v;
            } else {
                const float* xr = x + ((size_t)(b0 + b) * LN + lp) * FN;
                uint_t o[4];
#pragma unroll
                for (int p = 0; p < 4; ++p) {
                    float a0 = bxs[ch * 8 + 2 * p], a1 = bxs[ch * 8 + 2 * p + 1];
#pragma unroll
                    for (int f = 0; f < FN; ++f) {
                        float xv = xr[f];
                        a0 += xv * wxs[ch * 8 + 2 * p][f];
                        a1 += xv * wxs[ch * 8 + 2 * p + 1][f];
                    }
                    o[p] = pk2(fmaxf(a0, 0.0f), fmaxf(a1, 0.0f));
                }
                *(uint4*)&actf[dst] = make_uint4(o[0], o[1], o[2], o[3]);
            }
        }
        __syncthreads();

        // ---- Phase B: fz kstep + pointwise + stores
        {
            h8 B0 = *(const h8*)&actf[AIDX(cur, 0, 10) + ln * 8];
            h8 B1 = *(const h8*)&actf[AIDX(cur, 1, 10) + ln * 8];
            uint4 aw;
            aw = WL[(RB + mtA * 11 + 10) * 64]; ra0 = MFMA(bch8(aw), B0, ra0); ra1 = MFMA(bch8(aw), B1, ra1);
            aw = WL[(RB + mtB * 11 + 10) * 64]; rb0 = MFMA(bch8(aw), B0, rb0); rb1 = MFMA(bch8(aw), B1, rb1);
            aw = WL[(ZB + mtA * 11 + 10) * 64]; za0 = MFMA(bch8(aw), B0, za0); za1 = MFMA(bch8(aw), B1, za1);
            aw = WL[(ZB + mtB * 11 + 10) * 64]; zb0 = MFMA(bch8(aw), B0, zb0); zb1 = MFMA(bch8(aw), B1, zb1);
            aw = WL[(IB + mtA * 3 + 2) * 64];   ia0 = MFMA(bch8(aw), B0, ia0); ia1 = MFMA(bch8(aw), B1, ia1);
            aw = WL[(IB + mtB * 3 + 2) * 64];   ib0 = MFMA(bch8(aw), B0, ib0); ib1 = MFMA(bch8(aw), B1, ib1);
            if (w < 6) {
                aw = WL[(TB + (w >> 1) * 9 + 0) * 64];
                tp = MFMA(bch8(aw), (w & 1) ? B1 : B0, tp);
            }
        }

#define PW(RACC, ZACC, NACC, IACC, MTL, NTV) do {                                   \
        int jb = (2 * w + (MTL)) * 16 + ((ln >> 4) << 2);                           \
        int abase = (((jb >> 3) & 3) * 16 + (ln & 15)) * 8 + (jb & 7);              \
        uint2 ho2 = *(const uint2*)&actf[AIDX(cur, (NTV), jb >> 5) + abase];        \
        float ho[4] = { h2f((ushort_t)ho2.x), h2f((ushort_t)(ho2.x >> 16)),         \
                        h2f((ushort_t)ho2.y), h2f((ushort_t)(ho2.y >> 16)) };       \
        float hn4[4];                                                               \
        _Pragma("unroll")                                                           \
        for (int q = 0; q < 4; ++q) {                                               \
            float r_ = sigmoidf_((RACC)[q] + bsr[jb + q]);                          \
            float z_ = sigmoidf_((ZACC)[q] + bsz[jb + q]);                          \
            float n_ = tanhf((IACC)[q] + bin_[jb + q] + r_ * ((NACC)[q] + bhn_[jb + q])); \
            hn4[q] = (1.0f - z_) * n_ + z_ * ho[q];                                 \
        }                                                                           \
        uint2 hw2; hw2.x = pk2(hn4[0], hn4[1]); hw2.y = pk2(hn4[2], hn4[3]);        \
        *(uint2*)&actf[AIDX(nxt, (NTV), jb >> 5) + abase] = hw2;                    \
    } while (0)

        PW(ra0, za0, na0, ia0, 0, 0);
        PW(ra1, za1, na1, ia1, 0, 1);
        PW(rb0, zb0, nb0, ib0, 1, 0);
        PW(rb1, zb1, nb1, ib1, 1, 1);
#undef PW

        if (w < 6) {    // theta store
            int bb = b0 + (w & 1) * 16 + (ln & 15);
            float* op = out + ((size_t)bb * LN + l) * FN;
#pragma unroll
            for (int q = 0; q < 4; ++q) {
                int f = (w >> 1) * 16 + ((ln >> 4) << 2) + q;
                if (f < FN) op[f] = tp[q] + btls[f];
            }
        }
        __syncthreads();
    }
}

extern "C" void kernel_launch(void* const* d_in, const int* in_sizes, int n_in,
                              void* d_out, int out_size, void* d_ws, size_t ws_size,
                              hipStream_t stream) {
    const float* x        = (const float*)d_in[0];
    const float* eps      = (const float*)d_in[1];
    const float* Wx       = (const float*)d_in[2];
    const float* bx       = (const float*)d_in[3];
    const float* Wz1      = (const float*)d_in[4];
    const float* bz1      = (const float*)d_in[5];
    const float* Wz2      = (const float*)d_in[6];
    const float* bz2      = (const float*)d_in[7];
    const float* Wp_loc   = (const float*)d_in[8];
    const float* bp_loc   = (const float*)d_in[9];
    const float* Wp_scale = (const float*)d_in[10];
    const float* bp_scale = (const float*)d_in[11];
    const float* Wt_loc   = (const float*)d_in[12];
    const float* bt_loc   = (const float*)d_in[13];
    const float* W_ih     = (const float*)d_in[16];
    const float* W_hh     = (const float*)d_in[17];
    const float* b_ih     = (const float*)d_in[18];
    const float* b_hh     = (const float*)d_in[19];
    float* out = (float*)d_out;

    const size_t wfS = (size_t)NENT * 512;        // shorts
    const size_t fxS = (size_t)BN * LN * FXN;     // shorts

    ushort_t* wfrag = (ushort_t*)d_ws;
    ushort_t* fxbuf = wfrag + wfS;

    repack_frags<<<(int)((wfS + 255) / 256), 256, 0, stream>>>(
        W_ih, W_hh, Wt_loc, Wp_loc, Wp_scale, wfrag);

    if (ws_size >= (wfS + fxS) * sizeof(ushort_t)) {
        fx_pre<<<BN * LN / 256, 256, 0, stream>>>(x, Wx, bx, fxbuf);
        vrnn_mfma<true><<<NWG, NT, 0, stream>>>(
            x, eps, Wx, bx, Wz1, bz1, Wz2, bz2, bp_loc, bp_scale, bt_loc,
            b_ih, b_hh, wfrag, fxbuf, out);
    } else {
        vrnn_mfma<false><<<NWG, NT, 0, stream>>>(
            x, eps, Wx, bx, Wz1, bz1, Wz2, bz2, bp_loc, bp_scale, bt_loc,
            b_ih, b_hh, wfrag, (const ushort_t*)nullptr, out);
    }
}